// Round 1
// baseline (2314.610 us; speedup 1.0000x reference)
//
#include <hip/hip_runtime.h>
#include <math.h>

#define D_MODEL 768
#define D_INNER 1536
#define D_STATE 16
#define D_CONV 4
#define DT_RANK 48
#define N_LAYER 3
#define BATCH 2
#define SEQLEN 1024
#define NROWS (BATCH * SEQLEN)   // 2048
#define XDBL_W (DT_RANK + 2 * D_STATE)  // 80
#define EPS 1e-5f

// ---------------- add + rmsnorm ----------------
// row per block (768 cols, 256 threads x 3)
__global__ __launch_bounds__(256) void add_rmsnorm_kernel(
    const float* __restrict__ x, const float* __restrict__ res_in,
    const float* __restrict__ w, float* __restrict__ res_out,
    float* __restrict__ normed)
{
    int row = blockIdx.x;
    int tid = threadIdx.x;
    const float* xr = x + row * D_MODEL;
    float v[3];
    float ss = 0.f;
#pragma unroll
    for (int i = 0; i < 3; i++) {
        int c = tid + i * 256;
        float t = xr[c];
        if (res_in) t += res_in[row * D_MODEL + c];
        v[i] = t;
        ss += t * t;
    }
    for (int off = 32; off; off >>= 1) ss += __shfl_xor(ss, off, 64);
    __shared__ float red[4];
    if ((tid & 63) == 0) red[tid >> 6] = ss;
    __syncthreads();
    float tot = red[0] + red[1] + red[2] + red[3];
    float scale = rsqrtf(tot * (1.f / D_MODEL) + EPS);
#pragma unroll
    for (int i = 0; i < 3; i++) {
        int c = tid + i * 256;
        if (res_out) res_out[row * D_MODEL + c] = v[i];
        normed[row * D_MODEL + c] = v[i] * scale * w[c];
    }
}

// ---------------- generic f32 GEMM: C[M,N] = A[M,K] * W[N,K]^T ----------------
// 64x64 tile, BK=16, 256 threads, 4x4 per thread.
// EPI: 0 = none, 1 = softplus(acc + bias[n])
template <int EPI>
__global__ __launch_bounds__(256) void gemm_kernel(
    const float* __restrict__ A, int lda,
    const float* __restrict__ W,
    const float* __restrict__ bias,
    float* __restrict__ C, int ldc,
    int M, int N, int K)
{
    __shared__ float As[16][64];
    __shared__ float Ws[16][64];
    int tid = threadIdx.x;
    int row0 = blockIdx.y * 64;
    int col0 = blockIdx.x * 64;
    int lm = tid >> 2;        // 0..63
    int lk = (tid & 3) * 4;   // 0,4,8,12
    int ty = tid >> 4, tx = tid & 15;
    float acc[4][4] = {};
    const float* Arow = A + (size_t)(row0 + lm) * lda + lk;  // M divisible by 64
    const float* Wrow = W + (size_t)(col0 + lm) * K + lk;
    bool wvalid = (col0 + lm) < N;

    for (int k0 = 0; k0 < K; k0 += 16) {
        float4 av = *(const float4*)(Arow + k0);
        float4 wv = wvalid ? *(const float4*)(Wrow + k0) : make_float4(0.f, 0.f, 0.f, 0.f);
        __syncthreads();
        As[lk + 0][lm] = av.x; As[lk + 1][lm] = av.y;
        As[lk + 2][lm] = av.z; As[lk + 3][lm] = av.w;
        Ws[lk + 0][lm] = wv.x; Ws[lk + 1][lm] = wv.y;
        Ws[lk + 2][lm] = wv.z; Ws[lk + 3][lm] = wv.w;
        __syncthreads();
#pragma unroll
        for (int k = 0; k < 16; k++) {
            float4 a = *(const float4*)&As[k][ty * 4];
            float4 b = *(const float4*)&Ws[k][tx * 4];
            float ar[4] = {a.x, a.y, a.z, a.w};
            float br[4] = {b.x, b.y, b.z, b.w};
#pragma unroll
            for (int i = 0; i < 4; i++)
#pragma unroll
                for (int j = 0; j < 4; j++) acc[i][j] += ar[i] * br[j];
        }
    }
#pragma unroll
    for (int i = 0; i < 4; i++) {
        int r = row0 + ty * 4 + i;
#pragma unroll
        for (int j = 0; j < 4; j++) {
            int c = col0 + tx * 4 + j;
            if (c < N) {
                float v = acc[i][j];
                if (EPI == 1) {
                    v += bias[c];
                    v = (v > 20.f) ? v : log1pf(__expf(v));
                }
                C[(size_t)r * ldc + c] = v;
            }
        }
    }
}

// ---------------- depthwise causal conv1d (k=4) + SiLU ----------------
// x is the first D_INNER cols of xz (row stride 2*D_INNER)
__global__ __launch_bounds__(256) void conv_silu_kernel(
    const float* __restrict__ xz, const float* __restrict__ cw,
    const float* __restrict__ cb, float* __restrict__ out)
{
    int idx = blockIdx.x * 256 + threadIdx.x;   // B*L*D_INNER total, divisible
    int d = idx % D_INNER;
    int bl = idx / D_INNER;   // b*SEQLEN + l
    int l = bl % SEQLEN;
    float s = cb[d];
    const float* xp = xz + (size_t)bl * (2 * D_INNER) + d;
#pragma unroll
    for (int k = 0; k < D_CONV; k++) {
        int ls = l - (D_CONV - 1) + k;
        if (ls >= 0) s += cw[d * D_CONV + k] * xp[(k - (D_CONV - 1)) * (2 * D_INNER)];
    }
    out[(size_t)bl * D_INNER + d] = s / (1.f + __expf(-s));  // silu
}

// ---------------- selective scan ----------------
// 16 lanes per (b,d) channel (one per state n); block=256 -> 16 channels.
// grid = BATCH * (D_INNER/16). In-place y over u is safe (each (b,l,d) written
// by its own lane group after its reads).
__global__ __launch_bounds__(256) void scan_kernel(
    const float* __restrict__ u, const float* __restrict__ delta,
    const float* __restrict__ A_log, const float* __restrict__ xdbl,
    const float* __restrict__ Dskip, const float* __restrict__ xz,
    float* __restrict__ y)
{
    int tid = threadIdx.x;
    int n = tid & 15;
    int dsub = tid >> 4;  // 0..15
    int b = blockIdx.x / (D_INNER / 16);
    int d = (blockIdx.x % (D_INNER / 16)) * 16 + dsub;
    float a = -__expf(A_log[d * D_STATE + n]);
    float dsk = Dskip[d];
    const float* dp = delta + (size_t)b * SEQLEN * D_INNER + d;
    const float* up = u + (size_t)b * SEQLEN * D_INNER + d;
    const float* bp = xdbl + (size_t)b * SEQLEN * XDBL_W + DT_RANK + n;
    const float* cp = bp + D_STATE;
    const float* zp = xz + (size_t)b * SEQLEN * (2 * D_INNER) + D_INNER + d;
    float* yp = y + (size_t)b * SEQLEN * D_INNER + d;

    float h = 0.f;
    float dt = dp[0], uu = up[0], Bn = bp[0], Cn = cp[0], zz = zp[0];
    for (int l = 0; l < SEQLEN; l++) {
        float ndt = 0.f, nuu = 0.f, nBn = 0.f, nCn = 0.f, nzz = 0.f;
        if (l + 1 < SEQLEN) {   // prefetch next step before the serial chain
            ndt = dp[(l + 1) * D_INNER];
            nuu = up[(l + 1) * D_INNER];
            nBn = bp[(l + 1) * XDBL_W];
            nCn = cp[(l + 1) * XDBL_W];
            nzz = zp[(l + 1) * (2 * D_INNER)];
        }
        h = __expf(dt * a) * h + (dt * uu) * Bn;
        float p = h * Cn;
        p += __shfl_xor(p, 1, 64);
        p += __shfl_xor(p, 2, 64);
        p += __shfl_xor(p, 4, 64);
        p += __shfl_xor(p, 8, 64);
        if (n == 0) {
            float yy = p + uu * dsk;
            yp[l * D_INNER] = yy * (zz / (1.f + __expf(-zz)));
        }
        dt = ndt; uu = nuu; Bn = nBn; Cn = nCn; zz = nzz;
    }
}

extern "C" void kernel_launch(void* const* d_in, const int* in_sizes, int n_in,
                              void* d_out, int out_size, void* d_ws, size_t ws_size,
                              hipStream_t stream)
{
    const float* hs        = (const float*)d_in[0];
    const float* norm_w    = (const float*)d_in[1];
    const float* in_proj_w = (const float*)d_in[2];
    const float* conv_w    = (const float*)d_in[3];
    const float* conv_b    = (const float*)d_in[4];
    const float* x_proj_w  = (const float*)d_in[5];
    const float* dt_proj_w = (const float*)d_in[6];
    const float* dt_proj_b = (const float*)d_in[7];
    const float* A_log     = (const float*)d_in[8];
    const float* D_skip    = (const float*)d_in[9];
    const float* out_proj_w= (const float*)d_in[10];
    const float* norm_f_w  = (const float*)d_in[11];

    float* ws = (float*)d_ws;
    float* residual = ws;                                   // 2048*768
    float* hidden   = residual + NROWS * D_MODEL;           // 2048*768
    float* xz       = hidden + NROWS * D_MODEL;             // 2048*3072
    float* xconv    = xz + NROWS * 2 * D_INNER;             // 2048*1536 (also y, in place)
    float* xdbl     = xconv + NROWS * D_INNER;              // 2048*80
    float* delta    = xdbl + NROWS * XDBL_W;                // 2048*1536

    for (int i = 0; i < N_LAYER; i++) {
        // residual (+)= hidden ; hidden = rmsnorm(residual)*w
        add_rmsnorm_kernel<<<NROWS, 256, 0, stream>>>(
            i == 0 ? hs : hidden, i == 0 ? nullptr : residual,
            norm_w + i * D_MODEL, residual, hidden);
        // xz = hidden @ in_proj_w^T   (2048 x 3072, K=768)
        gemm_kernel<0><<<dim3(48, 32), 256, 0, stream>>>(
            hidden, D_MODEL, in_proj_w + (size_t)i * 2 * D_INNER * D_MODEL,
            nullptr, xz, 2 * D_INNER, NROWS, 2 * D_INNER, D_MODEL);
        // xconv = silu(causal_conv(x))
        conv_silu_kernel<<<NROWS * D_INNER / 256, 256, 0, stream>>>(
            xz, conv_w + i * D_INNER * D_CONV, conv_b + i * D_INNER, xconv);
        // xdbl = xconv @ x_proj_w^T   (2048 x 80, K=1536)
        gemm_kernel<0><<<dim3(2, 32), 256, 0, stream>>>(
            xconv, D_INNER, x_proj_w + (size_t)i * XDBL_W * D_INNER,
            nullptr, xdbl, XDBL_W, NROWS, XDBL_W, D_INNER);
        // delta = softplus(xdbl[:, :48] @ dt_proj_w^T + b)  (2048 x 1536, K=48)
        gemm_kernel<1><<<dim3(24, 32), 256, 0, stream>>>(
            xdbl, XDBL_W, dt_proj_w + (size_t)i * D_INNER * DT_RANK,
            dt_proj_b + i * D_INNER, delta, D_INNER, NROWS, D_INNER, DT_RANK);
        // selective scan + gate: y (in place over xconv)
        scan_kernel<<<BATCH * (D_INNER / 16), 256, 0, stream>>>(
            xconv, delta, A_log + (size_t)i * D_INNER * D_STATE, xdbl,
            D_skip + i * D_INNER, xz, xconv);
        // hidden = y @ out_proj_w^T   (2048 x 768, K=1536)
        gemm_kernel<0><<<dim3(12, 32), 256, 0, stream>>>(
            xconv, D_INNER, out_proj_w + (size_t)i * D_MODEL * D_INNER,
            nullptr, hidden, D_MODEL, NROWS, D_MODEL, D_INNER);
    }
    // final: out = rmsnorm(hidden + residual) * norm_f_w
    add_rmsnorm_kernel<<<NROWS, 256, 0, stream>>>(
        hidden, residual, norm_f_w, nullptr, (float*)d_out);
}

// Round 2
// 1488.981 us; speedup vs baseline: 1.5545x; 1.5545x over previous
//
#include <hip/hip_runtime.h>
#include <math.h>

#define D_MODEL 768
#define D_INNER 1536
#define D_STATE 16
#define D_CONV 4
#define DT_RANK 48
#define N_LAYER 3
#define BATCH 2
#define SEQLEN 1024
#define NROWS (BATCH * SEQLEN)   // 2048
#define XDBL_W (DT_RANK + 2 * D_STATE)  // 80
#define EPS 1e-5f

#define SCHUNKS 64   // chunks over SEQLEN
#define SCLEN 16     // steps per chunk (SCHUNKS*SCLEN == SEQLEN)
#define SD 4         // d-channels per block (SD*SCHUNKS == 256 threads)

// ---------------- add + rmsnorm ----------------
__global__ __launch_bounds__(256) void add_rmsnorm_kernel(
    const float* __restrict__ x, const float* __restrict__ res_in,
    const float* __restrict__ w, float* __restrict__ res_out,
    float* __restrict__ normed)
{
    int row = blockIdx.x;
    int tid = threadIdx.x;
    const float* xr = x + row * D_MODEL;
    float v[3];
    float ss = 0.f;
#pragma unroll
    for (int i = 0; i < 3; i++) {
        int c = tid + i * 256;
        float t = xr[c];
        if (res_in) t += res_in[row * D_MODEL + c];
        v[i] = t;
        ss += t * t;
    }
    for (int off = 32; off; off >>= 1) ss += __shfl_xor(ss, off, 64);
    __shared__ float red[4];
    if ((tid & 63) == 0) red[tid >> 6] = ss;
    __syncthreads();
    float tot = red[0] + red[1] + red[2] + red[3];
    float scale = rsqrtf(tot * (1.f / D_MODEL) + EPS);
#pragma unroll
    for (int i = 0; i < 3; i++) {
        int c = tid + i * 256;
        if (res_out) res_out[row * D_MODEL + c] = v[i];
        normed[row * D_MODEL + c] = v[i] * scale * w[c];
    }
}

// ---------------- generic f32 GEMM: C[M,N] = A[M,K] * W[N,K]^T ----------------
template <int EPI>
__global__ __launch_bounds__(256) void gemm_kernel(
    const float* __restrict__ A, int lda,
    const float* __restrict__ W,
    const float* __restrict__ bias,
    float* __restrict__ C, int ldc,
    int M, int N, int K)
{
    __shared__ float As[16][64];
    __shared__ float Ws[16][64];
    int tid = threadIdx.x;
    int row0 = blockIdx.y * 64;
    int col0 = blockIdx.x * 64;
    int lm = tid >> 2;
    int lk = (tid & 3) * 4;
    int ty = tid >> 4, tx = tid & 15;
    float acc[4][4] = {};
    const float* Arow = A + (size_t)(row0 + lm) * lda + lk;
    const float* Wrow = W + (size_t)(col0 + lm) * K + lk;
    bool wvalid = (col0 + lm) < N;

    for (int k0 = 0; k0 < K; k0 += 16) {
        float4 av = *(const float4*)(Arow + k0);
        float4 wv = wvalid ? *(const float4*)(Wrow + k0) : make_float4(0.f, 0.f, 0.f, 0.f);
        __syncthreads();
        As[lk + 0][lm] = av.x; As[lk + 1][lm] = av.y;
        As[lk + 2][lm] = av.z; As[lk + 3][lm] = av.w;
        Ws[lk + 0][lm] = wv.x; Ws[lk + 1][lm] = wv.y;
        Ws[lk + 2][lm] = wv.z; Ws[lk + 3][lm] = wv.w;
        __syncthreads();
#pragma unroll
        for (int k = 0; k < 16; k++) {
            float4 a = *(const float4*)&As[k][ty * 4];
            float4 b = *(const float4*)&Ws[k][tx * 4];
            float ar[4] = {a.x, a.y, a.z, a.w};
            float br[4] = {b.x, b.y, b.z, b.w};
#pragma unroll
            for (int i = 0; i < 4; i++)
#pragma unroll
                for (int j = 0; j < 4; j++) acc[i][j] += ar[i] * br[j];
        }
    }
#pragma unroll
    for (int i = 0; i < 4; i++) {
        int r = row0 + ty * 4 + i;
#pragma unroll
        for (int j = 0; j < 4; j++) {
            int c = col0 + tx * 4 + j;
            if (c < N) {
                float v = acc[i][j];
                if (EPI == 1) {
                    v += bias[c];
                    v = (v > 20.f) ? v : log1pf(__expf(v));
                }
                C[(size_t)r * ldc + c] = v;
            }
        }
    }
}

// ---------------- depthwise causal conv1d (k=4) + SiLU ----------------
__global__ __launch_bounds__(256) void conv_silu_kernel(
    const float* __restrict__ xz, const float* __restrict__ cw,
    const float* __restrict__ cb, float* __restrict__ out)
{
    int idx = blockIdx.x * 256 + threadIdx.x;
    int d = idx % D_INNER;
    int bl = idx / D_INNER;
    int l = bl % SEQLEN;
    float s = cb[d];
    const float* xp = xz + (size_t)bl * (2 * D_INNER) + d;
#pragma unroll
    for (int k = 0; k < D_CONV; k++) {
        int ls = l - (D_CONV - 1) + k;
        if (ls >= 0) s += cw[d * D_CONV + k] * xp[(k - (D_CONV - 1)) * (2 * D_INNER)];
    }
    out[(size_t)bl * D_INNER + d] = s / (1.f + __expf(-s));
}

// ---------------- chunked selective scan ----------------
// One thread owns one (b, d, chunk) with all 16 states in registers.
// Phase 1: per-chunk transfer (P,H) with h0=0. LDS compose gives each chunk
// its true incoming state. Phase 2: rescan with h0, reduce over n in-register,
// gate with silu(z), store y (in place over u — safe: this block's phase-1
// reads of u complete before any phase-2 write, and u[b,l,d] is touched only
// by this block's thread (d, chunk(l))).
__global__ __launch_bounds__(256) void scan_chunked_kernel(
    const float* __restrict__ u, const float* __restrict__ delta,
    const float* __restrict__ A_log, const float* __restrict__ xdbl,
    const float* __restrict__ Dskip, const float* __restrict__ xz,
    float* __restrict__ y)
{
    __shared__ float Pl[SD * SCHUNKS * D_STATE];  // 16 KB
    __shared__ float Hl[SD * SCHUNKS * D_STATE];  // 16 KB
    const int t = threadIdx.x;
    const int dsub = t & (SD - 1);
    const int c = t >> 2;                 // chunk 0..63
    const int b = blockIdx.x / (D_INNER / SD);
    const int d = (blockIdx.x % (D_INNER / SD)) * SD + dsub;

    float a2[D_STATE];
#pragma unroll
    for (int n = 0; n < D_STATE; n++)
        a2[n] = -__expf(A_log[d * D_STATE + n]) * 1.44269504f;  // ln->log2 folded

    const size_t chbase = (size_t)b * SEQLEN * D_INNER + d;
    const float* dtp = delta + chbase;
    const float* up  = u + chbase;
    const float* xrow = xdbl + (size_t)b * SEQLEN * XDBL_W;
    const int l0 = c * SCLEN;

    float h[D_STATE], P[D_STATE];
#pragma unroll
    for (int n = 0; n < D_STATE; n++) { h[n] = 0.f; P[n] = 1.f; }

    // ---- phase 1: chunk transfer ----
    for (int i = 0; i < SCLEN; i++) {
        const int l = l0 + i;
        float dt = dtp[(size_t)l * D_INNER];
        float uu = up[(size_t)l * D_INNER];
        const float4* Bv = (const float4*)(xrow + (size_t)l * XDBL_W + DT_RANK);
        float4 q0 = Bv[0], q1 = Bv[1], q2 = Bv[2], q3 = Bv[3];
        float Bf[D_STATE] = {q0.x,q0.y,q0.z,q0.w, q1.x,q1.y,q1.z,q1.w,
                             q2.x,q2.y,q2.z,q2.w, q3.x,q3.y,q3.z,q3.w};
        float dtu = dt * uu;
#pragma unroll
        for (int n = 0; n < D_STATE; n++) {
            float e = __builtin_amdgcn_exp2f(dt * a2[n]);
            P[n] *= e;
            h[n] = e * h[n] + dtu * Bf[n];
        }
    }
    {
        const int base = (dsub * SCHUNKS + c) * D_STATE;
#pragma unroll
        for (int n = 0; n < D_STATE; n++) { Pl[base + n] = P[n]; Hl[base + n] = h[n]; }
    }
    __syncthreads();

    // ---- compose: serial prefix over chunks, one thread per (d,n) ----
    if (t < SD * D_STATE) {
        const int d2 = t >> 4, n2 = t & 15;
        float hin = 0.f;
        for (int cc = 0; cc < SCHUNKS; cc++) {
            const int idx = (d2 * SCHUNKS + cc) * D_STATE + n2;
            float Pc = Pl[idx], Hc = Hl[idx];
            Hl[idx] = hin;                 // incoming state for chunk cc
            hin = Pc * hin + Hc;
        }
    }
    __syncthreads();

    // ---- phase 2: rescan with true h0, emit y ----
    {
        const int base = (dsub * SCHUNKS + c) * D_STATE;
#pragma unroll
        for (int n = 0; n < D_STATE; n++) h[n] = Hl[base + n];
    }
    const float Dsk = Dskip[d];
    const float* zp = xz + (size_t)b * SEQLEN * (2 * D_INNER) + D_INNER + d;
    float* yp = y + chbase;
    for (int i = 0; i < SCLEN; i++) {
        const int l = l0 + i;
        float dt = dtp[(size_t)l * D_INNER];
        float uu = up[(size_t)l * D_INNER];
        float zz = zp[(size_t)l * (2 * D_INNER)];
        const float4* Bv = (const float4*)(xrow + (size_t)l * XDBL_W + DT_RANK);
        float4 q0 = Bv[0], q1 = Bv[1], q2 = Bv[2], q3 = Bv[3];
        float4 r0 = Bv[4], r1 = Bv[5], r2 = Bv[6], r3 = Bv[7];
        float Bf[D_STATE] = {q0.x,q0.y,q0.z,q0.w, q1.x,q1.y,q1.z,q1.w,
                             q2.x,q2.y,q2.z,q2.w, q3.x,q3.y,q3.z,q3.w};
        float Cf[D_STATE] = {r0.x,r0.y,r0.z,r0.w, r1.x,r1.y,r1.z,r1.w,
                             r2.x,r2.y,r2.z,r2.w, r3.x,r3.y,r3.z,r3.w};
        float dtu = dt * uu;
        float acc = 0.f;
#pragma unroll
        for (int n = 0; n < D_STATE; n++) {
            float e = __builtin_amdgcn_exp2f(dt * a2[n]);
            h[n] = e * h[n] + dtu * Bf[n];
            acc += h[n] * Cf[n];
        }
        float yy = acc + uu * Dsk;
        float ee = __builtin_amdgcn_exp2f(-zz * 1.44269504f);
        float sil = zz * __builtin_amdgcn_rcpf(1.f + ee);
        yp[(size_t)l * D_INNER] = yy * sil;
    }
}

extern "C" void kernel_launch(void* const* d_in, const int* in_sizes, int n_in,
                              void* d_out, int out_size, void* d_ws, size_t ws_size,
                              hipStream_t stream)
{
    const float* hs        = (const float*)d_in[0];
    const float* norm_w    = (const float*)d_in[1];
    const float* in_proj_w = (const float*)d_in[2];
    const float* conv_w    = (const float*)d_in[3];
    const float* conv_b    = (const float*)d_in[4];
    const float* x_proj_w  = (const float*)d_in[5];
    const float* dt_proj_w = (const float*)d_in[6];
    const float* dt_proj_b = (const float*)d_in[7];
    const float* A_log     = (const float*)d_in[8];
    const float* D_skip    = (const float*)d_in[9];
    const float* out_proj_w= (const float*)d_in[10];
    const float* norm_f_w  = (const float*)d_in[11];

    float* ws = (float*)d_ws;
    float* residual = ws;
    float* hidden   = residual + NROWS * D_MODEL;
    float* xz       = hidden + NROWS * D_MODEL;
    float* xconv    = xz + NROWS * 2 * D_INNER;   // also y, in place
    float* xdbl     = xconv + NROWS * D_INNER;
    float* delta    = xdbl + NROWS * XDBL_W;

    for (int i = 0; i < N_LAYER; i++) {
        add_rmsnorm_kernel<<<NROWS, 256, 0, stream>>>(
            i == 0 ? hs : hidden, i == 0 ? nullptr : residual,
            norm_w + i * D_MODEL, residual, hidden);
        gemm_kernel<0><<<dim3(48, 32), 256, 0, stream>>>(
            hidden, D_MODEL, in_proj_w + (size_t)i * 2 * D_INNER * D_MODEL,
            nullptr, xz, 2 * D_INNER, NROWS, 2 * D_INNER, D_MODEL);
        conv_silu_kernel<<<NROWS * D_INNER / 256, 256, 0, stream>>>(
            xz, conv_w + i * D_INNER * D_CONV, conv_b + i * D_INNER, xconv);
        gemm_kernel<0><<<dim3(2, 32), 256, 0, stream>>>(
            xconv, D_INNER, x_proj_w + (size_t)i * XDBL_W * D_INNER,
            nullptr, xdbl, XDBL_W, NROWS, XDBL_W, D_INNER);
        gemm_kernel<1><<<dim3(24, 32), 256, 0, stream>>>(
            xdbl, XDBL_W, dt_proj_w + (size_t)i * D_INNER * DT_RANK,
            dt_proj_b + i * D_INNER, delta, D_INNER, NROWS, D_INNER, DT_RANK);
        scan_chunked_kernel<<<BATCH * (D_INNER / SD), 256, 0, stream>>>(
            xconv, delta, A_log + (size_t)i * D_INNER * D_STATE, xdbl,
            D_skip + i * D_INNER, xz, xconv);
        gemm_kernel<0><<<dim3(12, 32), 256, 0, stream>>>(
            xconv, D_INNER, out_proj_w + (size_t)i * D_MODEL * D_INNER,
            nullptr, hidden, D_MODEL, NROWS, D_MODEL, D_INNER);
    }
    add_rmsnorm_kernel<<<NROWS, 256, 0, stream>>>(
        hidden, residual, norm_f_w, nullptr, (float*)d_out);
}

// Round 3
// 887.498 us; speedup vs baseline: 2.6080x; 1.6777x over previous
//
#include <hip/hip_runtime.h>
#include <math.h>

#define D_MODEL 768
#define D_INNER 1536
#define D_STATE 16
#define D_CONV 4
#define DT_RANK 48
#define N_LAYER 3
#define BATCH 2
#define SEQLEN 1024
#define NROWS (BATCH * SEQLEN)   // 2048
#define XDBL_W (DT_RANK + 2 * D_STATE)  // 80
#define EPS 1e-5f

#define SCHUNKS 64
#define SCLEN 16
#define SD 4

typedef short bf16x8 __attribute__((ext_vector_type(8)));
typedef float f32x4 __attribute__((ext_vector_type(4)));

__device__ __forceinline__ ushort f2bf(float x) {
    union { float f; uint u; } v; v.f = x;
    uint r = v.u + 0x7fff + ((v.u >> 16) & 1);   // RNE
    return (ushort)(r >> 16);
}

__device__ __forceinline__ void gload_lds16(const void* g, void* l) {
    __builtin_amdgcn_global_load_lds(
        (const __attribute__((address_space(1))) unsigned int*)g,
        (__attribute__((address_space(3))) unsigned int*)l, 16, 0, 0);
}

// ---------------- f32 -> bf16 bulk convert (n4 = n/4) ----------------
__global__ __launch_bounds__(256) void cvt_bf16_kernel(
    const float* __restrict__ s, ushort* __restrict__ d, int n4)
{
    int i = blockIdx.x * 256 + threadIdx.x;
    if (i >= n4) return;
    float4 v = ((const float4*)s)[i];
    ushort4 o;
    o.x = f2bf(v.x); o.y = f2bf(v.y); o.z = f2bf(v.z); o.w = f2bf(v.w);
    ((ushort4*)d)[i] = o;
}

// ---------------- add + rmsnorm (bf16 and/or f32 out) ----------------
__global__ __launch_bounds__(256) void add_rmsnorm_kernel(
    const float* __restrict__ x, const float* __restrict__ res_in,
    const float* __restrict__ w, float* __restrict__ res_out,
    float* __restrict__ normed_f32, ushort* __restrict__ normed_bf)
{
    int row = blockIdx.x;
    int tid = threadIdx.x;
    const float* xr = x + row * D_MODEL;
    float v[3];
    float ss = 0.f;
#pragma unroll
    for (int i = 0; i < 3; i++) {
        int c = tid + i * 256;
        float t = xr[c];
        if (res_in) t += res_in[row * D_MODEL + c];
        v[i] = t;
        ss += t * t;
    }
    for (int off = 32; off; off >>= 1) ss += __shfl_xor(ss, off, 64);
    __shared__ float red[4];
    if ((tid & 63) == 0) red[tid >> 6] = ss;
    __syncthreads();
    float tot = red[0] + red[1] + red[2] + red[3];
    float scale = rsqrtf(tot * (1.f / D_MODEL) + EPS);
#pragma unroll
    for (int i = 0; i < 3; i++) {
        int c = tid + i * 256;
        if (res_out) res_out[row * D_MODEL + c] = v[i];
        float o = v[i] * scale * w[c];
        if (normed_f32) normed_f32[row * D_MODEL + c] = o;
        if (normed_bf)  normed_bf[row * D_MODEL + c] = f2bf(o);
    }
}

// ---------------- bf16 MFMA GEMM: C[M,N] = A[M,K] @ W[N,K]^T ----------------
// BK=64. XOR-swizzled LDS: granule (row r, logical g) stored at slot g^(r&7).
// global_load_lds dest = wave base + lane*16 (phys-contiguous); we swizzle the
// SOURCE address per lane instead. ds_read_b128 fragment reads then hit each
// bank pair only 2-way (free).
template <int BM, int BN>
__global__ __launch_bounds__(256) void gemm_mfma_kernel(
    const ushort* __restrict__ A, const ushort* __restrict__ W,
    float* __restrict__ C, int M, int N, int K)
{
    constexpr int TM = BM / 32;   // m-tiles per wave (wave covers BM/2)
    constexpr int TN = BN / 32;
    __shared__ __attribute__((aligned(16))) ushort As[BM * 64];
    __shared__ __attribute__((aligned(16))) ushort Ws[BN * 64];
    const int t = threadIdx.x;
    const int lane = t & 63, w = t >> 6;
    const int ln15 = lane & 15, q = lane >> 4;
    const int row0 = blockIdx.y * BM, col0 = blockIdx.x * BN;
    const int wm0 = (w & 1) * (BM / 2), wn0 = (w >> 1) * (BN / 2);

    f32x4 acc[TM][TN];
#pragma unroll
    for (int i = 0; i < TM; i++)
#pragma unroll
        for (int j = 0; j < TN; j++) acc[i][j] = (f32x4){0.f, 0.f, 0.f, 0.f};

    for (int k0 = 0; k0 < K; k0 += 64) {
        __syncthreads();   // prior iter's LDS reads done before re-staging
#pragma unroll
        for (int i = 0; i < BM / 32; i++) {
            int p = (i * 4 + w) * 64 + lane;          // phys granule
            int r = p >> 3, s = p & 7;
            int g = s ^ (r & 7);                      // logical k-granule
            gload_lds16(A + (size_t)(row0 + r) * K + k0 + g * 8, &As[p * 8]);
        }
#pragma unroll
        for (int i = 0; i < BN / 32; i++) {
            int p = (i * 4 + w) * 64 + lane;
            int r = p >> 3, s = p & 7;
            int g = s ^ (r & 7);
            gload_lds16(W + (size_t)(col0 + r) * K + k0 + g * 8, &Ws[p * 8]);
        }
        __syncthreads();   // drains vmcnt (global_load_lds) too
#pragma unroll
        for (int ks = 0; ks < 2; ks++) {
            bf16x8 af[TM], wf[TN];
#pragma unroll
            for (int im = 0; im < TM; im++) {
                int m = wm0 + im * 16 + ln15;
                int slot = (ks * 4 + q) ^ (m & 7);
                af[im] = *(const bf16x8*)&As[m * 64 + slot * 8];
            }
#pragma unroll
            for (int jn = 0; jn < TN; jn++) {
                int n = wn0 + jn * 16 + ln15;
                int slot = (ks * 4 + q) ^ (n & 7);
                wf[jn] = *(const bf16x8*)&Ws[n * 64 + slot * 8];
            }
#pragma unroll
            for (int im = 0; im < TM; im++)
#pragma unroll
                for (int jn = 0; jn < TN; jn++)
                    acc[im][jn] = __builtin_amdgcn_mfma_f32_16x16x32_bf16(
                        af[im], wf[jn], acc[im][jn], 0, 0, 0);
        }
    }
    // epilogue: D row=(lane>>4)*4+reg (m), col=lane&15 (n)
#pragma unroll
    for (int im = 0; im < TM; im++) {
#pragma unroll
        for (int jn = 0; jn < TN; jn++) {
            int rr = row0 + wm0 + im * 16 + q * 4;
            int cc = col0 + wn0 + jn * 16 + ln15;
            float* cp = C + (size_t)rr * N + cc;
#pragma unroll
            for (int r = 0; r < 4; r++) cp[(size_t)r * N] = acc[im][jn][r];
        }
    }
}

// ---------------- generic f32 GEMM (kept for x_proj / dt_proj) ----------------
template <int EPI>
__global__ __launch_bounds__(256) void gemm_kernel(
    const float* __restrict__ A, int lda,
    const float* __restrict__ W,
    const float* __restrict__ bias,
    float* __restrict__ C, int ldc,
    int M, int N, int K)
{
    __shared__ float As[16][64];
    __shared__ float Wsh[16][64];
    int tid = threadIdx.x;
    int row0 = blockIdx.y * 64;
    int col0 = blockIdx.x * 64;
    int lm = tid >> 2;
    int lk = (tid & 3) * 4;
    int ty = tid >> 4, tx = tid & 15;
    float acc[4][4] = {};
    const float* Arow = A + (size_t)(row0 + lm) * lda + lk;
    const float* Wrow = W + (size_t)(col0 + lm) * K + lk;
    bool wvalid = (col0 + lm) < N;

    for (int k0 = 0; k0 < K; k0 += 16) {
        float4 av = *(const float4*)(Arow + k0);
        float4 wv = wvalid ? *(const float4*)(Wrow + k0) : make_float4(0.f, 0.f, 0.f, 0.f);
        __syncthreads();
        As[lk + 0][lm] = av.x; As[lk + 1][lm] = av.y;
        As[lk + 2][lm] = av.z; As[lk + 3][lm] = av.w;
        Wsh[lk + 0][lm] = wv.x; Wsh[lk + 1][lm] = wv.y;
        Wsh[lk + 2][lm] = wv.z; Wsh[lk + 3][lm] = wv.w;
        __syncthreads();
#pragma unroll
        for (int k = 0; k < 16; k++) {
            float4 a = *(const float4*)&As[k][ty * 4];
            float4 b = *(const float4*)&Wsh[k][tx * 4];
            float ar[4] = {a.x, a.y, a.z, a.w};
            float br[4] = {b.x, b.y, b.z, b.w};
#pragma unroll
            for (int i = 0; i < 4; i++)
#pragma unroll
                for (int j = 0; j < 4; j++) acc[i][j] += ar[i] * br[j];
        }
    }
#pragma unroll
    for (int i = 0; i < 4; i++) {
        int r = row0 + ty * 4 + i;
#pragma unroll
        for (int j = 0; j < 4; j++) {
            int c = col0 + tx * 4 + j;
            if (c < N) {
                float v = acc[i][j];
                if (EPI == 1) {
                    v += bias[c];
                    v = (v > 20.f) ? v : log1pf(__expf(v));
                }
                C[(size_t)r * ldc + c] = v;
            }
        }
    }
}

// ---------------- depthwise causal conv1d (k=4) + SiLU ----------------
__global__ __launch_bounds__(256) void conv_silu_kernel(
    const float* __restrict__ xz, const float* __restrict__ cw,
    const float* __restrict__ cb, float* __restrict__ out)
{
    int idx = blockIdx.x * 256 + threadIdx.x;
    int d = idx % D_INNER;
    int bl = idx / D_INNER;
    int l = bl % SEQLEN;
    float s = cb[d];
    const float* xp = xz + (size_t)bl * (2 * D_INNER) + d;
#pragma unroll
    for (int k = 0; k < D_CONV; k++) {
        int ls = l - (D_CONV - 1) + k;
        if (ls >= 0) s += cw[d * D_CONV + k] * xp[(k - (D_CONV - 1)) * (2 * D_INNER)];
    }
    out[(size_t)bl * D_INNER + d] = s / (1.f + __expf(-s));
}

// ---------------- chunked selective scan (bf16 y out) ----------------
__global__ __launch_bounds__(256) void scan_chunked_kernel(
    const float* __restrict__ u, const float* __restrict__ delta,
    const float* __restrict__ A_log, const float* __restrict__ xdbl,
    const float* __restrict__ Dskip, const float* __restrict__ xz,
    ushort* __restrict__ ybf)
{
    __shared__ float Pl[SD * SCHUNKS * D_STATE];
    __shared__ float Hl[SD * SCHUNKS * D_STATE];
    const int t = threadIdx.x;
    const int dsub = t & (SD - 1);
    const int c = t >> 2;
    const int b = blockIdx.x / (D_INNER / SD);
    const int d = (blockIdx.x % (D_INNER / SD)) * SD + dsub;

    float a2[D_STATE];
#pragma unroll
    for (int n = 0; n < D_STATE; n++)
        a2[n] = -__expf(A_log[d * D_STATE + n]) * 1.44269504f;

    const size_t chbase = (size_t)b * SEQLEN * D_INNER + d;
    const float* dtp = delta + chbase;
    const float* up  = u + chbase;
    const float* xrow = xdbl + (size_t)b * SEQLEN * XDBL_W;
    const int l0 = c * SCLEN;

    float h[D_STATE], P[D_STATE];
#pragma unroll
    for (int n = 0; n < D_STATE; n++) { h[n] = 0.f; P[n] = 1.f; }

    for (int i = 0; i < SCLEN; i++) {
        const int l = l0 + i;
        float dt = dtp[(size_t)l * D_INNER];
        float uu = up[(size_t)l * D_INNER];
        const float4* Bv = (const float4*)(xrow + (size_t)l * XDBL_W + DT_RANK);
        float4 q0 = Bv[0], q1 = Bv[1], q2 = Bv[2], q3 = Bv[3];
        float Bf[D_STATE] = {q0.x,q0.y,q0.z,q0.w, q1.x,q1.y,q1.z,q1.w,
                             q2.x,q2.y,q2.z,q2.w, q3.x,q3.y,q3.z,q3.w};
        float dtu = dt * uu;
#pragma unroll
        for (int n = 0; n < D_STATE; n++) {
            float e = __builtin_amdgcn_exp2f(dt * a2[n]);
            P[n] *= e;
            h[n] = e * h[n] + dtu * Bf[n];
        }
    }
    {
        const int base = (dsub * SCHUNKS + c) * D_STATE;
#pragma unroll
        for (int n = 0; n < D_STATE; n++) { Pl[base + n] = P[n]; Hl[base + n] = h[n]; }
    }
    __syncthreads();

    if (t < SD * D_STATE) {
        const int d2 = t >> 4, n2 = t & 15;
        float hin = 0.f;
        for (int cc = 0; cc < SCHUNKS; cc++) {
            const int idx = (d2 * SCHUNKS + cc) * D_STATE + n2;
            float Pc = Pl[idx], Hc = Hl[idx];
            Hl[idx] = hin;
            hin = Pc * hin + Hc;
        }
    }
    __syncthreads();

    {
        const int base = (dsub * SCHUNKS + c) * D_STATE;
#pragma unroll
        for (int n = 0; n < D_STATE; n++) h[n] = Hl[base + n];
    }
    const float Dsk = Dskip[d];
    const float* zp = xz + (size_t)b * SEQLEN * (2 * D_INNER) + D_INNER + d;
    ushort* yp = ybf + chbase;
    for (int i = 0; i < SCLEN; i++) {
        const int l = l0 + i;
        float dt = dtp[(size_t)l * D_INNER];
        float uu = up[(size_t)l * D_INNER];
        float zz = zp[(size_t)l * (2 * D_INNER)];
        const float4* Bv = (const float4*)(xrow + (size_t)l * XDBL_W + DT_RANK);
        float4 q0 = Bv[0], q1 = Bv[1], q2 = Bv[2], q3 = Bv[3];
        float4 r0 = Bv[4], r1 = Bv[5], r2 = Bv[6], r3 = Bv[7];
        float Bf[D_STATE] = {q0.x,q0.y,q0.z,q0.w, q1.x,q1.y,q1.z,q1.w,
                             q2.x,q2.y,q2.z,q2.w, q3.x,q3.y,q3.z,q3.w};
        float Cf[D_STATE] = {r0.x,r0.y,r0.z,r0.w, r1.x,r1.y,r1.z,r1.w,
                             r2.x,r2.y,r2.z,r2.w, r3.x,r3.y,r3.z,r3.w};
        float dtu = dt * uu;
        float acc = 0.f;
#pragma unroll
        for (int n = 0; n < D_STATE; n++) {
            float e = __builtin_amdgcn_exp2f(dt * a2[n]);
            h[n] = e * h[n] + dtu * Bf[n];
            acc += h[n] * Cf[n];
        }
        float yy = acc + uu * Dsk;
        float ee = __builtin_amdgcn_exp2f(-zz * 1.44269504f);
        float sil = zz * __builtin_amdgcn_rcpf(1.f + ee);
        yp[(size_t)l * D_INNER] = f2bf(yy * sil);
    }
}

extern "C" void kernel_launch(void* const* d_in, const int* in_sizes, int n_in,
                              void* d_out, int out_size, void* d_ws, size_t ws_size,
                              hipStream_t stream)
{
    const float* hs        = (const float*)d_in[0];
    const float* norm_w    = (const float*)d_in[1];
    const float* in_proj_w = (const float*)d_in[2];
    const float* conv_w    = (const float*)d_in[3];
    const float* conv_b    = (const float*)d_in[4];
    const float* x_proj_w  = (const float*)d_in[5];
    const float* dt_proj_w = (const float*)d_in[6];
    const float* dt_proj_b = (const float*)d_in[7];
    const float* A_log     = (const float*)d_in[8];
    const float* D_skip    = (const float*)d_in[9];
    const float* out_proj_w= (const float*)d_in[10];
    const float* norm_f_w  = (const float*)d_in[11];

    float* ws = (float*)d_ws;
    float* residual = ws;                                  // 2048*768
    float* hidden   = residual + NROWS * D_MODEL;          // 2048*768
    float* xz       = hidden + NROWS * D_MODEL;            // 2048*3072
    float* xconv    = xz + NROWS * 2 * D_INNER;            // 2048*1536
    float* xdbl     = xconv + NROWS * D_INNER;             // 2048*80
    float* delta    = xdbl + NROWS * XDBL_W;               // 2048*1536
    ushort* normbf  = (ushort*)(delta + NROWS * D_INNER);  // 2048*768
    ushort* ybf     = normbf + NROWS * D_MODEL;            // 2048*1536
    ushort* win_bf  = ybf + NROWS * D_INNER;               // 3*3072*768
    ushort* wout_bf = win_bf + (size_t)N_LAYER * 2 * D_INNER * D_MODEL; // 3*768*1536

    // convert weights once per launch
    {
        int n_in4  = N_LAYER * 2 * D_INNER * D_MODEL / 4;
        int n_out4 = N_LAYER * D_MODEL * D_INNER / 4;
        cvt_bf16_kernel<<<(n_in4 + 255) / 256, 256, 0, stream>>>(in_proj_w, win_bf, n_in4);
        cvt_bf16_kernel<<<(n_out4 + 255) / 256, 256, 0, stream>>>(out_proj_w, wout_bf, n_out4);
    }

    for (int i = 0; i < N_LAYER; i++) {
        add_rmsnorm_kernel<<<NROWS, 256, 0, stream>>>(
            i == 0 ? hs : hidden, i == 0 ? nullptr : residual,
            norm_w + i * D_MODEL, residual, nullptr, normbf);
        // xz = normed @ in_proj_w^T  (2048 x 3072, K=768) — bf16 MFMA
        gemm_mfma_kernel<128, 128><<<dim3(2 * D_INNER / 128, NROWS / 128), 256, 0, stream>>>(
            normbf, win_bf + (size_t)i * 2 * D_INNER * D_MODEL,
            xz, NROWS, 2 * D_INNER, D_MODEL);
        conv_silu_kernel<<<NROWS * D_INNER / 256, 256, 0, stream>>>(
            xz, conv_w + i * D_INNER * D_CONV, conv_b + i * D_INNER, xconv);
        gemm_kernel<0><<<dim3(2, 32), 256, 0, stream>>>(
            xconv, D_INNER, x_proj_w + (size_t)i * XDBL_W * D_INNER,
            nullptr, xdbl, XDBL_W, NROWS, XDBL_W, D_INNER);
        gemm_kernel<1><<<dim3(24, 32), 256, 0, stream>>>(
            xdbl, XDBL_W, dt_proj_w + (size_t)i * D_INNER * DT_RANK,
            dt_proj_b + i * D_INNER, delta, D_INNER, NROWS, D_INNER, DT_RANK);
        scan_chunked_kernel<<<BATCH * (D_INNER / SD), 256, 0, stream>>>(
            xconv, delta, A_log + (size_t)i * D_INNER * D_STATE, xdbl,
            D_skip + i * D_INNER, xz, ybf);
        // hidden = y @ out_proj_w^T  (2048 x 768, K=1536) — bf16 MFMA
        gemm_mfma_kernel<128, 64><<<dim3(D_MODEL / 64, NROWS / 128), 256, 0, stream>>>(
            ybf, wout_bf + (size_t)i * D_MODEL * D_INNER,
            hidden, NROWS, D_MODEL, D_INNER);
    }
    add_rmsnorm_kernel<<<NROWS, 256, 0, stream>>>(
        hidden, residual, norm_f_w, nullptr, (float*)d_out, nullptr);
}

// Round 4
// 564.797 us; speedup vs baseline: 4.0981x; 1.5714x over previous
//
#include <hip/hip_runtime.h>
#include <math.h>

#define D_MODEL 768
#define D_INNER 1536
#define D_STATE 16
#define D_CONV 4
#define DT_RANK 48
#define N_LAYER 3
#define BATCH 2
#define SEQLEN 1024
#define NROWS (BATCH * SEQLEN)   // 2048
#define XDBL_W (DT_RANK + 2 * D_STATE)  // 80
#define EPS 1e-5f

#define SCHUNKS 64
#define SCLEN 16
#define SDN 16      // d-channels per scan block (lane&15)
#define KSPLIT 4    // x_proj split-K factor
#define KSLICE (D_INNER / KSPLIT)   // 384

typedef short bf16x8 __attribute__((ext_vector_type(8)));
typedef float f32x4 __attribute__((ext_vector_type(4)));

__device__ __forceinline__ ushort f2bf(float x) {
    union { float f; uint u; } v; v.f = x;
    uint r = v.u + 0x7fff + ((v.u >> 16) & 1);   // RNE
    return (ushort)(r >> 16);
}

__device__ __forceinline__ void gload_lds16(const void* g, void* l) {
    __builtin_amdgcn_global_load_lds(
        (const __attribute__((address_space(1))) unsigned int*)g,
        (__attribute__((address_space(3))) unsigned int*)l, 16, 0, 0);
}

// ---------------- f32 -> bf16 bulk convert ----------------
__global__ __launch_bounds__(256) void cvt_bf16_kernel(
    const float* __restrict__ s, ushort* __restrict__ d, int n4)
{
    int i = blockIdx.x * 256 + threadIdx.x;
    if (i >= n4) return;
    float4 v = ((const float4*)s)[i];
    ushort4 o;
    o.x = f2bf(v.x); o.y = f2bf(v.y); o.z = f2bf(v.z); o.w = f2bf(v.w);
    ((ushort4*)d)[i] = o;
}

// ---------------- add + rmsnorm ----------------
__global__ __launch_bounds__(256) void add_rmsnorm_kernel(
    const float* __restrict__ x, const float* __restrict__ res_in,
    const float* __restrict__ w, float* __restrict__ res_out,
    float* __restrict__ normed_f32, ushort* __restrict__ normed_bf)
{
    int row = blockIdx.x;
    int tid = threadIdx.x;
    const float* xr = x + row * D_MODEL;
    float v[3];
    float ss = 0.f;
#pragma unroll
    for (int i = 0; i < 3; i++) {
        int c = tid + i * 256;
        float t = xr[c];
        if (res_in) t += res_in[row * D_MODEL + c];
        v[i] = t;
        ss += t * t;
    }
    for (int off = 32; off; off >>= 1) ss += __shfl_xor(ss, off, 64);
    __shared__ float red[4];
    if ((tid & 63) == 0) red[tid >> 6] = ss;
    __syncthreads();
    float tot = red[0] + red[1] + red[2] + red[3];
    float scale = rsqrtf(tot * (1.f / D_MODEL) + EPS);
#pragma unroll
    for (int i = 0; i < 3; i++) {
        int c = tid + i * 256;
        if (res_out) res_out[row * D_MODEL + c] = v[i];
        float o = v[i] * scale * w[c];
        if (normed_f32) normed_f32[row * D_MODEL + c] = o;
        if (normed_bf)  normed_bf[row * D_MODEL + c] = f2bf(o);
    }
}

// ---------------- bf16 MFMA GEMM: C[M,N] = A[M,K] @ W[N,K]^T ----------------
template <int BM, int BN>
__global__ __launch_bounds__(256) void gemm_mfma_kernel(
    const ushort* __restrict__ A, const ushort* __restrict__ W,
    float* __restrict__ C, int M, int N, int K)
{
    constexpr int TM = BM / 32;
    constexpr int TN = BN / 32;
    __shared__ __attribute__((aligned(16))) ushort As[BM * 64];
    __shared__ __attribute__((aligned(16))) ushort Ws[BN * 64];
    const int t = threadIdx.x;
    const int lane = t & 63, w = t >> 6;
    const int ln15 = lane & 15, q = lane >> 4;
    const int row0 = blockIdx.y * BM, col0 = blockIdx.x * BN;
    const int wm0 = (w & 1) * (BM / 2), wn0 = (w >> 1) * (BN / 2);

    f32x4 acc[TM][TN];
#pragma unroll
    for (int i = 0; i < TM; i++)
#pragma unroll
        for (int j = 0; j < TN; j++) acc[i][j] = (f32x4){0.f, 0.f, 0.f, 0.f};

    for (int k0 = 0; k0 < K; k0 += 64) {
        __syncthreads();
#pragma unroll
        for (int i = 0; i < BM / 32; i++) {
            int p = (i * 4 + w) * 64 + lane;
            int r = p >> 3, s = p & 7;
            int g = s ^ (r & 7);
            gload_lds16(A + (size_t)(row0 + r) * K + k0 + g * 8, &As[p * 8]);
        }
#pragma unroll
        for (int i = 0; i < BN / 32; i++) {
            int p = (i * 4 + w) * 64 + lane;
            int r = p >> 3, s = p & 7;
            int g = s ^ (r & 7);
            gload_lds16(W + (size_t)(col0 + r) * K + k0 + g * 8, &Ws[p * 8]);
        }
        __syncthreads();
#pragma unroll
        for (int ks = 0; ks < 2; ks++) {
            bf16x8 af[TM], wf[TN];
#pragma unroll
            for (int im = 0; im < TM; im++) {
                int m = wm0 + im * 16 + ln15;
                int slot = (ks * 4 + q) ^ (m & 7);
                af[im] = *(const bf16x8*)&As[m * 64 + slot * 8];
            }
#pragma unroll
            for (int jn = 0; jn < TN; jn++) {
                int n = wn0 + jn * 16 + ln15;
                int slot = (ks * 4 + q) ^ (n & 7);
                wf[jn] = *(const bf16x8*)&Ws[n * 64 + slot * 8];
            }
#pragma unroll
            for (int im = 0; im < TM; im++)
#pragma unroll
                for (int jn = 0; jn < TN; jn++)
                    acc[im][jn] = __builtin_amdgcn_mfma_f32_16x16x32_bf16(
                        af[im], wf[jn], acc[im][jn], 0, 0, 0);
        }
    }
#pragma unroll
    for (int im = 0; im < TM; im++) {
#pragma unroll
        for (int jn = 0; jn < TN; jn++) {
            int rr = row0 + wm0 + im * 16 + q * 4;
            int cc = col0 + wn0 + jn * 16 + ln15;
            float* cp = C + (size_t)rr * N + cc;
#pragma unroll
            for (int r = 0; r < 4; r++) cp[(size_t)r * N] = acc[im][jn][r];
        }
    }
}

// ---------------- generic f32 GEMM (dt_proj) ----------------
template <int EPI>
__global__ __launch_bounds__(256) void gemm_kernel(
    const float* __restrict__ A, int lda,
    const float* __restrict__ W,
    const float* __restrict__ bias,
    float* __restrict__ C, int ldc,
    int M, int N, int K)
{
    __shared__ float As[16][64];
    __shared__ float Wsh[16][64];
    int tid = threadIdx.x;
    int row0 = blockIdx.y * 64;
    int col0 = blockIdx.x * 64;
    int lm = tid >> 2;
    int lk = (tid & 3) * 4;
    int ty = tid >> 4, tx = tid & 15;
    float acc[4][4] = {};
    const float* Arow = A + (size_t)(row0 + lm) * lda + lk;
    const float* Wrow = W + (size_t)(col0 + lm) * K + lk;
    bool wvalid = (col0 + lm) < N;

    for (int k0 = 0; k0 < K; k0 += 16) {
        float4 av = *(const float4*)(Arow + k0);
        float4 wv = wvalid ? *(const float4*)(Wrow + k0) : make_float4(0.f, 0.f, 0.f, 0.f);
        __syncthreads();
        As[lk + 0][lm] = av.x; As[lk + 1][lm] = av.y;
        As[lk + 2][lm] = av.z; As[lk + 3][lm] = av.w;
        Wsh[lk + 0][lm] = wv.x; Wsh[lk + 1][lm] = wv.y;
        Wsh[lk + 2][lm] = wv.z; Wsh[lk + 3][lm] = wv.w;
        __syncthreads();
#pragma unroll
        for (int k = 0; k < 16; k++) {
            float4 a = *(const float4*)&As[k][ty * 4];
            float4 b = *(const float4*)&Wsh[k][tx * 4];
            float ar[4] = {a.x, a.y, a.z, a.w};
            float br[4] = {b.x, b.y, b.z, b.w};
#pragma unroll
            for (int i = 0; i < 4; i++)
#pragma unroll
                for (int j = 0; j < 4; j++) acc[i][j] += ar[i] * br[j];
        }
    }
#pragma unroll
    for (int i = 0; i < 4; i++) {
        int r = row0 + ty * 4 + i;
#pragma unroll
        for (int j = 0; j < 4; j++) {
            int c = col0 + tx * 4 + j;
            if (c < N) {
                float v = acc[i][j];
                if (EPI == 1) {
                    v += bias[c];
                    v = (v > 20.f) ? v : log1pf(__expf(v));
                }
                C[(size_t)r * ldc + c] = v;
            }
        }
    }
}

// ---------------- x_proj split-K partial GEMM ----------------
// Cp[z][M][80] partial over K slice z. Grid (2, 32, KSPLIT).
__global__ __launch_bounds__(256) void gemm_xpart_kernel(
    const float* __restrict__ A, const float* __restrict__ W,
    float* __restrict__ Cp)
{
    __shared__ float As[16][64];
    __shared__ float Wsh[16][64];
    int tid = threadIdx.x;
    int row0 = blockIdx.y * 64;
    int col0 = blockIdx.x * 64;
    int kz = blockIdx.z * KSLICE;
    int lm = tid >> 2;
    int lk = (tid & 3) * 4;
    int ty = tid >> 4, tx = tid & 15;
    float acc[4][4] = {};
    const float* Arow = A + (size_t)(row0 + lm) * D_INNER + kz + lk;
    const float* Wrow = W + (size_t)(col0 + lm) * D_INNER + kz + lk;
    bool wvalid = (col0 + lm) < XDBL_W;

    for (int k0 = 0; k0 < KSLICE; k0 += 16) {
        float4 av = *(const float4*)(Arow + k0);
        float4 wv = wvalid ? *(const float4*)(Wrow + k0) : make_float4(0.f, 0.f, 0.f, 0.f);
        __syncthreads();
        As[lk + 0][lm] = av.x; As[lk + 1][lm] = av.y;
        As[lk + 2][lm] = av.z; As[lk + 3][lm] = av.w;
        Wsh[lk + 0][lm] = wv.x; Wsh[lk + 1][lm] = wv.y;
        Wsh[lk + 2][lm] = wv.z; Wsh[lk + 3][lm] = wv.w;
        __syncthreads();
#pragma unroll
        for (int k = 0; k < 16; k++) {
            float4 a = *(const float4*)&As[k][ty * 4];
            float4 b = *(const float4*)&Wsh[k][tx * 4];
            float ar[4] = {a.x, a.y, a.z, a.w};
            float br[4] = {b.x, b.y, b.z, b.w};
#pragma unroll
            for (int i = 0; i < 4; i++)
#pragma unroll
                for (int j = 0; j < 4; j++) acc[i][j] += ar[i] * br[j];
        }
    }
    float* Co = Cp + (size_t)blockIdx.z * NROWS * XDBL_W;
#pragma unroll
    for (int i = 0; i < 4; i++) {
        int r = row0 + ty * 4 + i;
#pragma unroll
        for (int j = 0; j < 4; j++) {
            int c = col0 + tx * 4 + j;
            if (c < XDBL_W) Co[(size_t)r * XDBL_W + c] = acc[i][j];
        }
    }
}

__global__ __launch_bounds__(256) void xreduce_kernel(
    const float* __restrict__ Cp, float* __restrict__ xdbl)
{
    int i = blockIdx.x * 256 + threadIdx.x;   // over NROWS*XDBL_W/4
    const int S4 = NROWS * XDBL_W / 4;
    if (i >= S4) return;
    const float4* p = (const float4*)Cp;
    float4 a = p[i], b = p[i + S4], c = p[i + 2 * S4], d = p[i + 3 * S4];
    float4 o;
    o.x = a.x + b.x + c.x + d.x;
    o.y = a.y + b.y + c.y + d.y;
    o.z = a.z + b.z + c.z + d.z;
    o.w = a.w + b.w + c.w + d.w;
    ((float4*)xdbl)[i] = o;
}

// ---------------- depthwise causal conv1d (k=4) + SiLU ----------------
__global__ __launch_bounds__(256) void conv_silu_kernel(
    const float* __restrict__ xz, const float* __restrict__ cw,
    const float* __restrict__ cb, float* __restrict__ out)
{
    int idx = blockIdx.x * 256 + threadIdx.x;
    int d = idx % D_INNER;
    int bl = idx / D_INNER;
    int l = bl % SEQLEN;
    float s = cb[d];
    const float* xp = xz + (size_t)bl * (2 * D_INNER) + d;
#pragma unroll
    for (int k = 0; k < D_CONV; k++) {
        int ls = l - (D_CONV - 1) + k;
        if (ls >= 0) s += cw[d * D_CONV + k] * xp[(k - (D_CONV - 1)) * (2 * D_INNER)];
    }
    out[(size_t)bl * D_INNER + d] = s / (1.f + __expf(-s));
}

// ---------------- coalesced chunked selective scan ----------------
// 1024 threads: dsub = lane&15 (16 consecutive d -> 64B coalesced loads),
// csub = lane>>4 (4 chunks/wave), 16 waves -> 64 chunks. Hierarchical
// compose: intra-wave shfl scan + LDS cross-wave serial compose.
__global__ __launch_bounds__(1024) void scan2_kernel(
    const float* __restrict__ u, const float* __restrict__ delta,
    const float* __restrict__ A_log, const float* __restrict__ xdbl,
    const float* __restrict__ Dskip, const float* __restrict__ xz,
    ushort* __restrict__ ybf)
{
    __shared__ float PL[16][SDN * 17];   // [wave][dsub*17 + n] padded stride
    __shared__ float HL[16][SDN * 17];
    const int t = threadIdx.x;
    const int lane = t & 63;
    const int w = t >> 6;             // wave 0..15
    const int dsub = lane & 15;
    const int csub = lane >> 4;       // 0..3
    const int c = w * 4 + csub;       // chunk 0..63
    const int b = blockIdx.x / (D_INNER / SDN);
    const int d = (blockIdx.x % (D_INNER / SDN)) * SDN + dsub;

    float a2[D_STATE];
#pragma unroll
    for (int n = 0; n < D_STATE; n++)
        a2[n] = -__expf(A_log[d * D_STATE + n]) * 1.44269504f;

    const size_t base = (size_t)b * SEQLEN * D_INNER + d;
    const float* dtp = delta + base;
    const float* up  = u + base;
    const float* xrow = xdbl + (size_t)b * SEQLEN * XDBL_W;
    const int l0 = c * SCLEN;

    float h[D_STATE], P[D_STATE];
#pragma unroll
    for (int n = 0; n < D_STATE; n++) { h[n] = 0.f; P[n] = 1.f; }

    // ---- phase 1: chunk transfer (h with h0=0, P = prod of decay) ----
    for (int i = 0; i < SCLEN; i++) {
        const int l = l0 + i;
        float dt = dtp[(size_t)l * D_INNER];
        float uu = up[(size_t)l * D_INNER];
        const float4* Bv = (const float4*)(xrow + (size_t)l * XDBL_W + DT_RANK);
        float4 q0 = Bv[0], q1 = Bv[1], q2 = Bv[2], q3 = Bv[3];
        float Bf[D_STATE] = {q0.x,q0.y,q0.z,q0.w, q1.x,q1.y,q1.z,q1.w,
                             q2.x,q2.y,q2.z,q2.w, q3.x,q3.y,q3.z,q3.w};
        float dtu = dt * uu;
#pragma unroll
        for (int n = 0; n < D_STATE; n++) {
            float e = __builtin_amdgcn_exp2f(dt * a2[n]);
            P[n] *= e;
            h[n] = e * h[n] + dtu * Bf[n];
        }
    }

    // ---- intra-wave inclusive scan over csub (Hillis-Steele, 2 steps) ----
#pragma unroll
    for (int n = 0; n < D_STATE; n++) {
        float Pp = __shfl(P[n], lane - 16, 64);
        float Hp = __shfl(h[n], lane - 16, 64);
        bool act = csub >= 1;
        h[n] = act ? P[n] * Hp + h[n] : h[n];
        P[n] = act ? P[n] * Pp : P[n];
    }
#pragma unroll
    for (int n = 0; n < D_STATE; n++) {
        float Pp = __shfl(P[n], lane - 32, 64);
        float Hp = __shfl(h[n], lane - 32, 64);
        bool act = csub >= 2;
        h[n] = act ? P[n] * Hp + h[n] : h[n];
        P[n] = act ? P[n] * Pp : P[n];
    }

    // ---- wave totals -> LDS ----
    if (csub == 3) {
#pragma unroll
        for (int n = 0; n < D_STATE; n++) {
            PL[w][dsub * 17 + n] = P[n];
            HL[w][dsub * 17 + n] = h[n];
        }
    }
    __syncthreads();

    // ---- cross-wave serial compose: HL[w] becomes wave-incoming state ----
    if (t < SDN * D_STATE) {
        const int d2 = t >> 4, n2 = t & 15;
        float hin = 0.f;
        for (int ww = 0; ww < 16; ww++) {
            float Pw = PL[ww][d2 * 17 + n2];
            float Hw = HL[ww][d2 * 17 + n2];
            HL[ww][d2 * 17 + n2] = hin;
            hin = Pw * hin + Hw;
        }
    }
    __syncthreads();

    // ---- per-thread chunk-incoming state via exclusive intra-wave prefix ----
#pragma unroll
    for (int n = 0; n < D_STATE; n++) {
        float Win = HL[w][dsub * 17 + n];
        float Pe = __shfl(P[n], lane - 16, 64);   // inclusive prefix of csub-1
        float He = __shfl(h[n], lane - 16, 64);
        h[n] = (csub == 0) ? Win : Pe * Win + He;
    }

    // ---- phase 2: rescan with true h0, emit y ----
    const float Dsk = Dskip[d];
    const float* zp = xz + (size_t)b * SEQLEN * (2 * D_INNER) + D_INNER + d;
    ushort* yp = ybf + base;
    for (int i = 0; i < SCLEN; i++) {
        const int l = l0 + i;
        float dt = dtp[(size_t)l * D_INNER];
        float uu = up[(size_t)l * D_INNER];
        float zz = zp[(size_t)l * (2 * D_INNER)];
        const float4* Bv = (const float4*)(xrow + (size_t)l * XDBL_W + DT_RANK);
        float4 q0 = Bv[0], q1 = Bv[1], q2 = Bv[2], q3 = Bv[3];
        float4 r0 = Bv[4], r1 = Bv[5], r2 = Bv[6], r3 = Bv[7];
        float Bf[D_STATE] = {q0.x,q0.y,q0.z,q0.w, q1.x,q1.y,q1.z,q1.w,
                             q2.x,q2.y,q2.z,q2.w, q3.x,q3.y,q3.z,q3.w};
        float Cf[D_STATE] = {r0.x,r0.y,r0.z,r0.w, r1.x,r1.y,r1.z,r1.w,
                             r2.x,r2.y,r2.z,r2.w, r3.x,r3.y,r3.z,r3.w};
        float dtu = dt * uu;
        float acc = 0.f;
#pragma unroll
        for (int n = 0; n < D_STATE; n++) {
            float e = __builtin_amdgcn_exp2f(dt * a2[n]);
            h[n] = e * h[n] + dtu * Bf[n];
            acc += h[n] * Cf[n];
        }
        float yy = acc + uu * Dsk;
        float ee = __builtin_amdgcn_exp2f(-zz * 1.44269504f);
        float sil = zz * __builtin_amdgcn_rcpf(1.f + ee);
        yp[(size_t)l * D_INNER] = f2bf(yy * sil);
    }
}

extern "C" void kernel_launch(void* const* d_in, const int* in_sizes, int n_in,
                              void* d_out, int out_size, void* d_ws, size_t ws_size,
                              hipStream_t stream)
{
    const float* hs        = (const float*)d_in[0];
    const float* norm_w    = (const float*)d_in[1];
    const float* in_proj_w = (const float*)d_in[2];
    const float* conv_w    = (const float*)d_in[3];
    const float* conv_b    = (const float*)d_in[4];
    const float* x_proj_w  = (const float*)d_in[5];
    const float* dt_proj_w = (const float*)d_in[6];
    const float* dt_proj_b = (const float*)d_in[7];
    const float* A_log     = (const float*)d_in[8];
    const float* D_skip    = (const float*)d_in[9];
    const float* out_proj_w= (const float*)d_in[10];
    const float* norm_f_w  = (const float*)d_in[11];

    float* ws = (float*)d_ws;
    float* residual = ws;                                  // 2048*768
    float* hidden   = residual + NROWS * D_MODEL;          // 2048*768
    float* xz       = hidden + NROWS * D_MODEL;            // 2048*3072
    float* xconv    = xz + NROWS * 2 * D_INNER;            // 2048*1536
    float* xdbl     = xconv + NROWS * D_INNER;             // 2048*80
    float* delta    = xdbl + NROWS * XDBL_W;               // 2048*1536
    float* xpart    = delta + NROWS * D_INNER;             // 4*2048*80
    ushort* normbf  = (ushort*)(xpart + KSPLIT * NROWS * XDBL_W); // 2048*768
    ushort* ybf     = normbf + NROWS * D_MODEL;            // 2048*1536
    ushort* win_bf  = ybf + NROWS * D_INNER;               // 3*3072*768
    ushort* wout_bf = win_bf + (size_t)N_LAYER * 2 * D_INNER * D_MODEL; // 3*768*1536

    {
        int n_in4  = N_LAYER * 2 * D_INNER * D_MODEL / 4;
        int n_out4 = N_LAYER * D_MODEL * D_INNER / 4;
        cvt_bf16_kernel<<<(n_in4 + 255) / 256, 256, 0, stream>>>(in_proj_w, win_bf, n_in4);
        cvt_bf16_kernel<<<(n_out4 + 255) / 256, 256, 0, stream>>>(out_proj_w, wout_bf, n_out4);
    }

    for (int i = 0; i < N_LAYER; i++) {
        add_rmsnorm_kernel<<<NROWS, 256, 0, stream>>>(
            i == 0 ? hs : hidden, i == 0 ? nullptr : residual,
            norm_w + i * D_MODEL, residual, nullptr, normbf);
        gemm_mfma_kernel<128, 128><<<dim3(2 * D_INNER / 128, NROWS / 128), 256, 0, stream>>>(
            normbf, win_bf + (size_t)i * 2 * D_INNER * D_MODEL,
            xz, NROWS, 2 * D_INNER, D_MODEL);
        conv_silu_kernel<<<NROWS * D_INNER / 256, 256, 0, stream>>>(
            xz, conv_w + i * D_INNER * D_CONV, conv_b + i * D_INNER, xconv);
        // x_proj: split-K partials + reduce
        gemm_xpart_kernel<<<dim3(2, 32, KSPLIT), 256, 0, stream>>>(
            xconv, x_proj_w + (size_t)i * XDBL_W * D_INNER, xpart);
        xreduce_kernel<<<(NROWS * XDBL_W / 4 + 255) / 256, 256, 0, stream>>>(
            xpart, xdbl);
        gemm_kernel<1><<<dim3(24, 32), 256, 0, stream>>>(
            xdbl, XDBL_W, dt_proj_w + (size_t)i * D_INNER * DT_RANK,
            dt_proj_b + i * D_INNER, delta, D_INNER, NROWS, D_INNER, DT_RANK);
        scan2_kernel<<<BATCH * (D_INNER / SDN), 1024, 0, stream>>>(
            xconv, delta, A_log + (size_t)i * D_INNER * D_STATE, xdbl,
            D_skip + i * D_INNER, xz, ybf);
        gemm_mfma_kernel<128, 64><<<dim3(D_MODEL / 64, NROWS / 128), 256, 0, stream>>>(
            ybf, wout_bf + (size_t)i * D_MODEL * D_INNER,
            hidden, NROWS, D_MODEL, D_INNER);
    }
    add_rmsnorm_kernel<<<NROWS, 256, 0, stream>>>(
        hidden, residual, norm_f_w, nullptr, (float*)d_out, nullptr);
}

// Round 6
// 497.907 us; speedup vs baseline: 4.6487x; 1.1343x over previous
//
#include <hip/hip_runtime.h>
#include <math.h>

#define D_MODEL 768
#define D_INNER 1536
#define D_STATE 16
#define D_CONV 4
#define DT_RANK 48
#define N_LAYER 3
#define BATCH 2
#define SEQLEN 1024
#define NROWS (BATCH * SEQLEN)   // 2048
#define XDBL_W (DT_RANK + 2 * D_STATE)  // 80
#define EPS 1e-5f

#define SCLEN 16
#define SDN 16                   // d-channels per scan block
#define KSPLIT_X 8               // x_proj split-K

typedef short bf16x8 __attribute__((ext_vector_type(8)));
typedef float f32x4 __attribute__((ext_vector_type(4)));

__device__ __forceinline__ ushort f2bf(float x) {
    union { float f; uint u; } v; v.f = x;
    uint r = v.u + 0x7fff + ((v.u >> 16) & 1);   // RNE
    return (ushort)(r >> 16);
}

__device__ __forceinline__ void gload_lds16(const void* g, void* l) {
    __builtin_amdgcn_global_load_lds(
        (const __attribute__((address_space(1))) unsigned int*)g,
        (__attribute__((address_space(3))) unsigned int*)l, 16, 0, 0);
}

// ---------------- f32 -> bf16 bulk convert ----------------
__global__ __launch_bounds__(256) void cvt_bf16_kernel(
    const float* __restrict__ s, ushort* __restrict__ d, int n4)
{
    int i = blockIdx.x * 256 + threadIdx.x;
    if (i >= n4) return;
    float4 v = ((const float4*)s)[i];
    ushort4 o;
    o.x = f2bf(v.x); o.y = f2bf(v.y); o.z = f2bf(v.z); o.w = f2bf(v.w);
    ((ushort4*)d)[i] = o;
}

// x_proj weights: [3][80][1536] f32 -> [3][128][1536] bf16 (rows >=80 zero)
__global__ __launch_bounds__(256) void cvt_xw_pad_kernel(
    const float* __restrict__ src, ushort* __restrict__ dst)
{
    const int per = 128 * 1536 / 4;
    int i = blockIdx.x * 256 + threadIdx.x;
    if (i >= 3 * per) return;
    int li = i / per, rem = i - li * per;
    int r = (rem * 4) / 1536, c = (rem * 4) % 1536;
    ushort4 o = make_ushort4(0, 0, 0, 0);
    if (r < XDBL_W) {
        const float* s = src + ((size_t)li * XDBL_W + r) * 1536 + c;
        o.x = f2bf(s[0]); o.y = f2bf(s[1]); o.z = f2bf(s[2]); o.w = f2bf(s[3]);
    }
    ((ushort4*)dst)[i] = o;
}

// dt_proj weights: [3][1536][48] f32 -> [3][1536][64] bf16 (cols >=48 zero)
__global__ __launch_bounds__(256) void cvt_dtw_pad_kernel(
    const float* __restrict__ src, ushort* __restrict__ dst)
{
    const int per = 1536 * 64 / 4;
    int i = blockIdx.x * 256 + threadIdx.x;
    if (i >= 3 * per) return;
    int li = i / per, rem = i - li * per;
    int r = (rem * 4) / 64, c = (rem * 4) % 64;
    ushort4 o = make_ushort4(0, 0, 0, 0);
    if (c < DT_RANK) {
        const float* s = src + ((size_t)li * 1536 + r) * DT_RANK + c;
        o.x = f2bf(s[0]); o.y = f2bf(s[1]); o.z = f2bf(s[2]); o.w = f2bf(s[3]);
    }
    ((ushort4*)dst)[i] = o;
}

// ---------------- add + rmsnorm ----------------
__global__ __launch_bounds__(256) void add_rmsnorm_kernel(
    const float* __restrict__ x, const float* __restrict__ res_in,
    const float* __restrict__ w, float* __restrict__ res_out,
    float* __restrict__ normed_f32, ushort* __restrict__ normed_bf)
{
    int row = blockIdx.x;
    int tid = threadIdx.x;
    const float* xr = x + row * D_MODEL;
    float v[3];
    float ss = 0.f;
#pragma unroll
    for (int i = 0; i < 3; i++) {
        int c = tid + i * 256;
        float t = xr[c];
        if (res_in) t += res_in[row * D_MODEL + c];
        v[i] = t;
        ss += t * t;
    }
    for (int off = 32; off; off >>= 1) ss += __shfl_xor(ss, off, 64);
    __shared__ float red[4];
    if ((tid & 63) == 0) red[tid >> 6] = ss;
    __syncthreads();
    float tot = red[0] + red[1] + red[2] + red[3];
    float scale = rsqrtf(tot * (1.f / D_MODEL) + EPS);
#pragma unroll
    for (int i = 0; i < 3; i++) {
        int c = tid + i * 256;
        if (res_out) res_out[row * D_MODEL + c] = v[i];
        float o = v[i] * scale * w[c];
        if (normed_f32) normed_f32[row * D_MODEL + c] = o;
        if (normed_bf)  normed_bf[row * D_MODEL + c] = f2bf(o);
    }
}

// ---------------- bf16 MFMA GEMM: C[M,N] = A[M,K] @ W[N,K]^T ----------------
// EPI: 0 none, 1 softplus(acc + bias[n]). SPLITK>1: blockIdx.z slices K and
// writes partial C at z*M*ldc.
template <int BM, int BN, int EPI, int SPLITK>
__global__ __launch_bounds__(256) void gemm_mfma_kernel(
    const ushort* __restrict__ A, const ushort* __restrict__ W,
    const float* __restrict__ bias, float* __restrict__ C,
    int ldc, int Nout, int M, int K)
{
    constexpr int TM = BM / 32;
    constexpr int TN = BN / 32;
    __shared__ __attribute__((aligned(16))) ushort As[BM * 64];
    __shared__ __attribute__((aligned(16))) ushort Ws[BN * 64];
    const int t = threadIdx.x;
    const int lane = t & 63, w = t >> 6;
    const int ln15 = lane & 15, q = lane >> 4;
    const int row0 = blockIdx.y * BM, col0 = blockIdx.x * BN;
    const int wm0 = (w & 1) * (BM / 2), wn0 = (w >> 1) * (BN / 2);

    int kper = K / SPLITK;
    int kz = (SPLITK > 1) ? blockIdx.z * kper : 0;
    if (SPLITK > 1) C += (size_t)blockIdx.z * M * ldc;

    f32x4 acc[TM][TN];
#pragma unroll
    for (int i = 0; i < TM; i++)
#pragma unroll
        for (int j = 0; j < TN; j++) acc[i][j] = (f32x4){0.f, 0.f, 0.f, 0.f};

    for (int k0 = kz; k0 < kz + kper; k0 += 64) {
        __syncthreads();
#pragma unroll
        for (int i = 0; i < BM / 32; i++) {
            int p = (i * 4 + w) * 64 + lane;
            int r = p >> 3, s = p & 7;
            int g = s ^ (r & 7);
            gload_lds16(A + (size_t)(row0 + r) * K + k0 + g * 8, &As[p * 8]);
        }
#pragma unroll
        for (int i = 0; i < BN / 32; i++) {
            int p = (i * 4 + w) * 64 + lane;
            int r = p >> 3, s = p & 7;
            int g = s ^ (r & 7);
            gload_lds16(W + (size_t)(col0 + r) * K + k0 + g * 8, &Ws[p * 8]);
        }
        __syncthreads();
#pragma unroll
        for (int ks = 0; ks < 2; ks++) {
            bf16x8 af[TM], wf[TN];
#pragma unroll
            for (int im = 0; im < TM; im++) {
                int m = wm0 + im * 16 + ln15;
                int slot = (ks * 4 + q) ^ (m & 7);
                af[im] = *(const bf16x8*)&As[m * 64 + slot * 8];
            }
#pragma unroll
            for (int jn = 0; jn < TN; jn++) {
                int n = wn0 + jn * 16 + ln15;
                int slot = (ks * 4 + q) ^ (n & 7);
                wf[jn] = *(const bf16x8*)&Ws[n * 64 + slot * 8];
            }
#pragma unroll
            for (int im = 0; im < TM; im++)
#pragma unroll
                for (int jn = 0; jn < TN; jn++)
                    acc[im][jn] = __builtin_amdgcn_mfma_f32_16x16x32_bf16(
                        af[im], wf[jn], acc[im][jn], 0, 0, 0);
        }
    }
#pragma unroll
    for (int im = 0; im < TM; im++) {
#pragma unroll
        for (int jn = 0; jn < TN; jn++) {
            int rr = row0 + wm0 + im * 16 + q * 4;
            int cc = col0 + wn0 + jn * 16 + ln15;
            if (cc < Nout) {
                float* cp = C + (size_t)rr * ldc + cc;
#pragma unroll
                for (int r = 0; r < 4; r++) {
                    float v = acc[im][jn][r];
                    if (EPI == 1) {
                        v += bias[cc];
                        v = (v > 20.f) ? v : log1pf(__expf(v));
                    }
                    cp[(size_t)r * ldc] = v;
                }
            }
        }
    }
}

// ---------------- x_proj split-K reduce: xdbl f32 + padded bf16 dt-part ----
__global__ __launch_bounds__(256) void xreduce_kernel(
    const float* __restrict__ Cp, float* __restrict__ xdbl,
    ushort* __restrict__ xdt)
{
    const int S4 = NROWS * XDBL_W / 4;
    int i = blockIdx.x * 256 + threadIdx.x;
    if (i >= S4) return;
    const float4* p = (const float4*)Cp;
    float4 o = p[i];
#pragma unroll
    for (int z = 1; z < KSPLIT_X; z++) {
        float4 a = p[i + (size_t)z * S4];
        o.x += a.x; o.y += a.y; o.z += a.z; o.w += a.w;
    }
    ((float4*)xdbl)[i] = o;
    int row = (i * 4) / XDBL_W, c0 = (i * 4) % XDBL_W;
    if (c0 < DT_RANK) {
        ushort4 b;
        b.x = f2bf(o.x); b.y = f2bf(o.y); b.z = f2bf(o.z); b.w = f2bf(o.w);
        *(ushort4*)&xdt[(size_t)row * 64 + c0] = b;
    } else if (c0 < 64) {
        *(ushort4*)&xdt[(size_t)row * 64 + c0] = make_ushort4(0, 0, 0, 0);
    }
}

// ---------------- depthwise causal conv1d (k=4) + SiLU (f32 + bf16 out) ----
__global__ __launch_bounds__(256) void conv_silu_kernel(
    const float* __restrict__ xz, const float* __restrict__ cw,
    const float* __restrict__ cb, float* __restrict__ out,
    ushort* __restrict__ out_bf)
{
    int idx = blockIdx.x * 256 + threadIdx.x;
    int d = idx % D_INNER;
    int bl = idx / D_INNER;
    int l = bl % SEQLEN;
    float s = cb[d];
    const float* xp = xz + (size_t)bl * (2 * D_INNER) + d;
#pragma unroll
    for (int k = 0; k < D_CONV; k++) {
        int ls = l - (D_CONV - 1) + k;
        if (ls >= 0) s += cw[d * D_CONV + k] * xp[(k - (D_CONV - 1)) * (2 * D_INNER)];
    }
    float sil = s / (1.f + __expf(-s));
    out[(size_t)bl * D_INNER + d] = sil;
    out_bf[(size_t)bl * D_INNER + d] = f2bf(sil);
}

// ---------------- coalesced chunked selective scan (proven round-4 form) ----
// 1024 threads: dsub = lane&15 (16 consecutive d -> 64B coalesced loads),
// csub = lane>>4 (4 chunks/wave), 16 waves -> 64 chunks. Hierarchical
// compose: intra-wave shfl scan + LDS cross-wave serial compose.
__global__ __launch_bounds__(1024) void scan2_kernel(
    const float* __restrict__ u, const float* __restrict__ delta,
    const float* __restrict__ A_log, const float* __restrict__ xdbl,
    const float* __restrict__ Dskip, const float* __restrict__ xz,
    ushort* __restrict__ ybf)
{
    __shared__ float PL[16][SDN * 17];
    __shared__ float HL[16][SDN * 17];
    const int t = threadIdx.x;
    const int lane = t & 63;
    const int w = t >> 6;             // wave 0..15
    const int dsub = lane & 15;
    const int csub = lane >> 4;       // 0..3
    const int c = w * 4 + csub;       // chunk 0..63
    const int b = blockIdx.x / (D_INNER / SDN);
    const int d = (blockIdx.x % (D_INNER / SDN)) * SDN + dsub;

    float a2[D_STATE];
#pragma unroll
    for (int n = 0; n < D_STATE; n++)
        a2[n] = -__expf(A_log[d * D_STATE + n]) * 1.44269504f;

    const size_t base = (size_t)b * SEQLEN * D_INNER + d;
    const float* dtp = delta + base;
    const float* up  = u + base;
    const float* xrow = xdbl + (size_t)b * SEQLEN * XDBL_W;
    const int l0 = c * SCLEN;

    float h[D_STATE], P[D_STATE];
#pragma unroll
    for (int n = 0; n < D_STATE; n++) { h[n] = 0.f; P[n] = 1.f; }

    // ---- phase 1: chunk transfer ----
    for (int i = 0; i < SCLEN; i++) {
        const int l = l0 + i;
        float dt = dtp[(size_t)l * D_INNER];
        float uu = up[(size_t)l * D_INNER];
        const float4* Bv = (const float4*)(xrow + (size_t)l * XDBL_W + DT_RANK);
        float4 q0 = Bv[0], q1 = Bv[1], q2 = Bv[2], q3 = Bv[3];
        float Bf[D_STATE] = {q0.x,q0.y,q0.z,q0.w, q1.x,q1.y,q1.z,q1.w,
                             q2.x,q2.y,q2.z,q2.w, q3.x,q3.y,q3.z,q3.w};
        float dtu = dt * uu;
#pragma unroll
        for (int n = 0; n < D_STATE; n++) {
            float e = __builtin_amdgcn_exp2f(dt * a2[n]);
            P[n] *= e;
            h[n] = e * h[n] + dtu * Bf[n];
        }
    }

    // ---- intra-wave inclusive scan over csub ----
#pragma unroll
    for (int n = 0; n < D_STATE; n++) {
        float Pp = __shfl(P[n], lane - 16, 64);
        float Hp = __shfl(h[n], lane - 16, 64);
        bool act = csub >= 1;
        h[n] = act ? P[n] * Hp + h[n] : h[n];
        P[n] = act ? P[n] * Pp : P[n];
    }
#pragma unroll
    for (int n = 0; n < D_STATE; n++) {
        float Pp = __shfl(P[n], lane - 32, 64);
        float Hp = __shfl(h[n], lane - 32, 64);
        bool act = csub >= 2;
        h[n] = act ? P[n] * Hp + h[n] : h[n];
        P[n] = act ? P[n] * Pp : P[n];
    }

    if (csub == 3) {
#pragma unroll
        for (int n = 0; n < D_STATE; n++) {
            PL[w][dsub * 17 + n] = P[n];
            HL[w][dsub * 17 + n] = h[n];
        }
    }
    __syncthreads();

    if (t < SDN * D_STATE) {
        const int d2 = t >> 4, n2 = t & 15;
        float hin = 0.f;
        for (int ww = 0; ww < 16; ww++) {
            float Pw = PL[ww][d2 * 17 + n2];
            float Hw = HL[ww][d2 * 17 + n2];
            HL[ww][d2 * 17 + n2] = hin;
            hin = Pw * hin + Hw;
        }
    }
    __syncthreads();

#pragma unroll
    for (int n = 0; n < D_STATE; n++) {
        float Win = HL[w][dsub * 17 + n];
        float Pe = __shfl(P[n], lane - 16, 64);
        float He = __shfl(h[n], lane - 16, 64);
        h[n] = (csub == 0) ? Win : Pe * Win + He;
    }

    // ---- phase 2: rescan with true h0, emit y ----
    const float Dsk = Dskip[d];
    const float* zp = xz + (size_t)b * SEQLEN * (2 * D_INNER) + D_INNER + d;
    ushort* yp = ybf + base;
    for (int i = 0; i < SCLEN; i++) {
        const int l = l0 + i;
        float dt = dtp[(size_t)l * D_INNER];
        float uu = up[(size_t)l * D_INNER];
        float zz = zp[(size_t)l * (2 * D_INNER)];
        const float4* Bv = (const float4*)(xrow + (size_t)l * XDBL_W + DT_RANK);
        float4 q0 = Bv[0], q1 = Bv[1], q2 = Bv[2], q3 = Bv[3];
        float4 r0 = Bv[4], r1 = Bv[5], r2 = Bv[6], r3 = Bv[7];
        float Bf[D_STATE] = {q0.x,q0.y,q0.z,q0.w, q1.x,q1.y,q1.z,q1.w,
                             q2.x,q2.y,q2.z,q2.w, q3.x,q3.y,q3.z,q3.w};
        float Cf[D_STATE] = {r0.x,r0.y,r0.z,r0.w, r1.x,r1.y,r1.z,r1.w,
                             r2.x,r2.y,r2.z,r2.w, r3.x,r3.y,r3.z,r3.w};
        float dtu = dt * uu;
        float acc = 0.f;
#pragma unroll
        for (int n = 0; n < D_STATE; n++) {
            float e = __builtin_amdgcn_exp2f(dt * a2[n]);
            h[n] = e * h[n] + dtu * Bf[n];
            acc += h[n] * Cf[n];
        }
        float yy = acc + uu * Dsk;
        float ee = __builtin_amdgcn_exp2f(-zz * 1.44269504f);
        float sil = zz * __builtin_amdgcn_rcpf(1.f + ee);
        yp[(size_t)l * D_INNER] = f2bf(yy * sil);
    }
}

extern "C" void kernel_launch(void* const* d_in, const int* in_sizes, int n_in,
                              void* d_out, int out_size, void* d_ws, size_t ws_size,
                              hipStream_t stream)
{
    const float* hs        = (const float*)d_in[0];
    const float* norm_w    = (const float*)d_in[1];
    const float* in_proj_w = (const float*)d_in[2];
    const float* conv_w    = (const float*)d_in[3];
    const float* conv_b    = (const float*)d_in[4];
    const float* x_proj_w  = (const float*)d_in[5];
    const float* dt_proj_w = (const float*)d_in[6];
    const float* dt_proj_b = (const float*)d_in[7];
    const float* A_log     = (const float*)d_in[8];
    const float* D_skip    = (const float*)d_in[9];
    const float* out_proj_w= (const float*)d_in[10];
    const float* norm_f_w  = (const float*)d_in[11];

    float* ws = (float*)d_ws;
    float* residual = ws;                                   // 2048*768
    float* hidden   = residual + NROWS * D_MODEL;           // 2048*768
    float* xz       = hidden + NROWS * D_MODEL;             // 2048*3072
    float* xconv    = xz + NROWS * 2 * D_INNER;             // 2048*1536
    float* xdbl     = xconv + NROWS * D_INNER;              // 2048*80
    float* delta    = xdbl + NROWS * XDBL_W;                // 2048*1536
    float* xpart    = delta + NROWS * D_INNER;              // 8*2048*80
    ushort* normbf  = (ushort*)(xpart + (size_t)KSPLIT_X * NROWS * XDBL_W);
    ushort* ybf     = normbf + NROWS * D_MODEL;             // 2048*1536
    ushort* xconvbf = ybf + NROWS * D_INNER;                // 2048*1536
    ushort* xdtbf   = xconvbf + NROWS * D_INNER;            // 2048*64
    ushort* win_bf  = xdtbf + NROWS * 64;                   // 3*3072*768
    ushort* wout_bf = win_bf + (size_t)N_LAYER * 2 * D_INNER * D_MODEL;
    ushort* xw_pad  = wout_bf + (size_t)N_LAYER * D_MODEL * D_INNER; // 3*128*1536
    ushort* dtw_pad = xw_pad + (size_t)N_LAYER * 128 * 1536;          // 3*1536*64

    {
        int n_in4  = N_LAYER * 2 * D_INNER * D_MODEL / 4;
        int n_out4 = N_LAYER * D_MODEL * D_INNER / 4;
        cvt_bf16_kernel<<<(n_in4 + 255) / 256, 256, 0, stream>>>(in_proj_w, win_bf, n_in4);
        cvt_bf16_kernel<<<(n_out4 + 255) / 256, 256, 0, stream>>>(out_proj_w, wout_bf, n_out4);
        cvt_xw_pad_kernel<<<(3 * 128 * 1536 / 4 + 255) / 256, 256, 0, stream>>>(x_proj_w, xw_pad);
        cvt_dtw_pad_kernel<<<(3 * 1536 * 64 / 4 + 255) / 256, 256, 0, stream>>>(dt_proj_w, dtw_pad);
    }

    for (int i = 0; i < N_LAYER; i++) {
        add_rmsnorm_kernel<<<NROWS, 256, 0, stream>>>(
            i == 0 ? hs : hidden, i == 0 ? nullptr : residual,
            norm_w + i * D_MODEL, residual, nullptr, normbf);
        // in_proj: 2048x3072, K=768 — 64x128 tiles, 768 blocks
        gemm_mfma_kernel<64, 128, 0, 1><<<dim3(2 * D_INNER / 128, NROWS / 64), 256, 0, stream>>>(
            normbf, win_bf + (size_t)i * 2 * D_INNER * D_MODEL, nullptr,
            xz, 2 * D_INNER, 2 * D_INNER, NROWS, D_MODEL);
        conv_silu_kernel<<<NROWS * D_INNER / 256, 256, 0, stream>>>(
            xz, conv_w + i * D_INNER * D_CONV, conv_b + i * D_INNER, xconv, xconvbf);
        // x_proj: 2048x80(pad128), K=1536, split-K x8 -> partials
        gemm_mfma_kernel<64, 128, 0, KSPLIT_X><<<dim3(1, NROWS / 64, KSPLIT_X), 256, 0, stream>>>(
            xconvbf, xw_pad + (size_t)i * 128 * 1536, nullptr,
            xpart, XDBL_W, XDBL_W, NROWS, D_INNER);
        xreduce_kernel<<<(NROWS * XDBL_W / 4 + 255) / 256, 256, 0, stream>>>(
            xpart, xdbl, xdtbf);
        // dt_proj: 2048x1536, K=64(pad) — softplus epilogue
        gemm_mfma_kernel<128, 128, 1, 1><<<dim3(D_INNER / 128, NROWS / 128), 256, 0, stream>>>(
            xdtbf, dtw_pad + (size_t)i * 1536 * 64, dt_proj_b + i * D_INNER,
            delta, D_INNER, D_INNER, NROWS, 64);
        scan2_kernel<<<BATCH * (D_INNER / SDN), 1024, 0, stream>>>(
            xconv, delta, A_log + (size_t)i * D_INNER * D_STATE, xdbl,
            D_skip + i * D_INNER, xz, ybf);
        // out_proj: 2048x768, K=1536 — 64x64 tiles, 384 blocks
        gemm_mfma_kernel<64, 64, 0, 1><<<dim3(D_MODEL / 64, NROWS / 64), 256, 0, stream>>>(
            ybf, wout_bf + (size_t)i * D_MODEL * D_INNER, nullptr,
            hidden, D_MODEL, D_MODEL, NROWS, D_INNER);
    }
    add_rmsnorm_kernel<<<NROWS, 256, 0, stream>>>(
        hidden, residual, norm_f_w, nullptr, (float*)d_out, nullptr);
}